// Round 9
// baseline (538.812 us; speedup 1.0000x reference)
//
#include <hip/hip_runtime.h>
#include <hip/hip_bf16.h>

#define BB 2
#define SS 2048
#define HH 1024
#define EE 8
#define KK 2
#define CAP 1536
#define NTOK (BB * SS)        // 4096
#define NASSIGN (NTOK * KK)   // 8192

// ---------------- workspace layout (float indices) ----------------
#define WS_PSUM   0            // 8
#define WS_AVG    8            // 2048  (fallback path full sums; unused in mfma path)
#define WS_HC     2056         // 2048  (raw pre-bias pre-relu, atomic target)
#define WS_ADJ    4104         // 16
#define WS_P1     4120         // 4096
#define WS_P2     8216         // 4096
#define WS_IDX    12312        // 4096 ints
#define WS_LOGITS 16408        // 32768: fallback logits OR avg partials (16*2*1024)
#define WS_ZERO_FLOATS 4112    // psum+avg+hc+adj head (zeroed by prep blk0 / memset)
#define WS_ZERO_BYTES 16448
#define WS_BF16_BYTE 196704    // bf16 planes start here (16B aligned)
// planes (4-term): Xh/Xm 2*8388608 B + Wh/Wm 2*2097152 B = 20971520 B
#define WS_H_BYTE (WS_BF16_BYTE + 31457280)   // plg partial logits (4MB used)
#define WS_NEED (WS_H_BYTE + 16777216ull)

using short8 = __attribute__((ext_vector_type(8))) short;
using u16x8  = __attribute__((ext_vector_type(8))) unsigned short;
using f32x4  = __attribute__((ext_vector_type(4))) float;

// ---- bf16 split helpers (manual RNE) ----
__device__ __forceinline__ unsigned short f2bf(float f) {
  unsigned u = __float_as_uint(f);
  unsigned r = (u + 0x7fffu + ((u >> 16) & 1u)) >> 16;
  return (unsigned short)r;
}
__device__ __forceinline__ float bf2f(unsigned short h) {
  return __uint_as_float((unsigned)h << 16);
}
// 2-way split: x ~= h + m with |x-(h+m)| <= 2^-17|x| (double-bf16).
__device__ __forceinline__ void split2(float x, unsigned short& h,
                                       unsigned short& m) {
  h = f2bf(x);
  m = f2bf(x - bf2f(h));
}

// async global->LDS, 16B per lane; lptr is wave-uniform base, HW adds lane*16
__device__ __forceinline__ void gload_lds16(const void* g, void* l) {
  __builtin_amdgcn_global_load_lds(
      (const __attribute__((address_space(1))) void*)g,
      (__attribute__((address_space(3))) void*)l, 16, 0, 0);
}

// ---------------- D1: consolidated prep dispatch ----------------
// blocks [0,4096): split X -> 2 bf16 planes (blk0 also zeros ws scalar head)
//                  AND NT-stream a 24KB slice of disp/comb zeros (R9: the
//                  403MB zero-fill moved here from the GEMM K-loop -- full
//                  chip parallelism, no barrier coupling; the GEMM's
//                  per-iter vmcnt(0) drain no longer waits on store acks).
// blocks [4096,4352): split+transpose w1 -> 2 bf16 planes
// blocks [4352,4480): avg partial sums (no atomics, no zero-init needed)
#define PREPX_BLKS 4096
#define PREPW_BLKS 256
#define AVG_BLKS   128
#define ZF4_PER_PREP 6144     // 25165824 f4 (disp+comb) / 4096 prep blocks
__global__ __launch_bounds__(256) void k_prep(
    const float* __restrict__ x, const float* __restrict__ w1,
    unsigned short* __restrict__ Xh, unsigned short* __restrict__ Xm,
    unsigned short* __restrict__ Wh, unsigned short* __restrict__ Wm,
    float* __restrict__ wshead, float* __restrict__ avg_part,
    f32x4* __restrict__ zout) {
  __shared__ unsigned short Th[64 * 65], Tm[64 * 65];
  int tid = threadIdx.x;
  int bid = blockIdx.x;
  if (bid < PREPX_BLKS) {
    if (bid == 0)
      for (int j = tid; j < WS_ZERO_FLOATS; j += 256) wshead[j] = 0.f;
    // zero-stream slice: 24 NT stores/thread, pure streaming (no barriers)
    {
      f32x4* zb = zout + (size_t)bid * ZF4_PER_PREP + tid;
      const f32x4 z4 = {0.f, 0.f, 0.f, 0.f};
#pragma unroll
      for (int j = 0; j < 24; ++j) __builtin_nontemporal_store(z4, &zb[j * 256]);
    }
    int i = (bid * 256 + tid) * 4;
    float4 v = *(const float4*)&x[i];
    unsigned short h[4], m[4];
    split2(v.x, h[0], m[0]);
    split2(v.y, h[1], m[1]);
    split2(v.z, h[2], m[2]);
    split2(v.w, h[3], m[3]);
    *(ushort4*)&Xh[i] = make_ushort4(h[0], h[1], h[2], h[3]);
    *(ushort4*)&Xm[i] = make_ushort4(m[0], m[1], m[2], m[3]);
  } else if (bid < PREPX_BLKS + PREPW_BLKS) {
    int pid = bid - PREPX_BLKS;
    int k0 = (pid & 15) * 64, n0 = (pid >> 4) * 64;
    for (int i = 0; i < 16; ++i) {
      int e = i * 256 + tid;
      int k = e >> 6, n = e & 63;
      float v = w1[(size_t)(k0 + k) * HH + n0 + n];
      unsigned short h, m;
      split2(v, h, m);
      Th[n * 65 + k] = h; Tm[n * 65 + k] = m;
    }
    __syncthreads();
    for (int i = 0; i < 16; ++i) {
      int e = i * 256 + tid;
      int n = e >> 6, k = e & 63;
      size_t o = (size_t)(n0 + n) * HH + k0 + k;
      Wh[o] = Th[n * 65 + k]; Wm[o] = Tm[n * 65 + k];
    }
  } else {
    int pid = bid - PREPX_BLKS - PREPW_BLKS;  // 0..127
    int h = (pid & 3) * 256 + tid;
    int c = (pid >> 2) & 15;
    int b = pid >> 6;
    const float* p = x + (size_t)b * SS * HH + (size_t)(c * 128) * HH + h;
    float s = 0.f;
    for (int i = 0; i < 128; ++i) s += p[(size_t)i * HH];
    avg_part[(c * BB + b) * HH + h] = s;   // raw partial sum
  }
}

// standalone avg-partials kernel (fallback path only)
__global__ void k_avgp(const float* __restrict__ x, float* __restrict__ avg_part) {
  int h = blockIdx.x * 256 + threadIdx.x;
  int c = blockIdx.y;
  int b = blockIdx.z;
  const float* p = x + (size_t)b * SS * HH + (size_t)(c * 128) * HH + h;
  float s = 0.f;
  for (int i = 0; i < 128; ++i) s += p[(size_t)i * HH];
  avg_part[(c * BB + b) * HH + h] = s;
}

// hc_raw += partial dot over i-chunk; reduces the 16 avg partials through LDS
__global__ void k_hc(const float* __restrict__ avg_part, const float* __restrict__ chr,
                     const float* __restrict__ wc1, float* __restrict__ hc_raw) {
  __shared__ float avg_s[128];
  int tid = threadIdx.x;
  int j = blockIdx.x * 256 + tid;
  int c = blockIdx.y;
  int b = blockIdx.z;
  if (tid < 128) {
    float s = 0.f;
    for (int cc = 0; cc < 16; ++cc)
      s += avg_part[(cc * BB + b) * HH + c * 128 + tid];
    avg_s[tid] = s * (1.0f / SS);
  }
  __syncthreads();
  float acc = 0.f;
  for (int il = 0; il < 128; ++il)
    acc += avg_s[il] * wc1[(size_t)(c * 128 + il) * HH + j];
  if (c == 7)
    for (int i = 0; i < EE; ++i)
      acc += chr[i] * wc1[(size_t)(HH + i) * HH + j];
  atomicAdd(&hc_raw[b * HH + j], acc);
}

// standalone adj kernel (fallback path only; mfma path runs adj inside D3)
__global__ void k_adj(const float* __restrict__ hc_raw, const float* __restrict__ bc1,
                      const float* __restrict__ wc2, const float* __restrict__ bc2,
                      float* __restrict__ adj) {
  int b = blockIdx.x;
  int tid = threadIdx.x;
  float part[EE] = {};
  for (int j = tid; j < HH; j += 256) {
    float v = fmaxf(hc_raw[b * HH + j] + bc1[j], 0.f);
    for (int e = 0; e < EE; ++e) part[e] += v * wc2[j * EE + e];
  }
  for (int m = 1; m < 64; m <<= 1)
    for (int e = 0; e < EE; ++e) part[e] += __shfl_xor(part[e], m);
  __shared__ float red[4][EE];
  int wave = tid >> 6, lane = tid & 63;
  if (lane == 0)
    for (int e = 0; e < EE; ++e) red[wave][e] = part[e];
  __syncthreads();
  if (tid < EE) {
    float s = bc2[tid];
    for (int w = 0; w < 4; ++w) s += red[w][tid];
    adj[b * EE + tid] = tanhf(s);
  }
}

// ---------------- D3: MFMA GEMM (R8 structure; zero-fill removed) --------
// SINGLE-VARIABLE EXPERIMENT vs R8: the in-loop NT zero stores moved to D1.
// The K-loop is now pure stage -> barrier -> MFMA; each iteration's
// vmcnt(0) drain covers only the 24 staging loads (L2-resident planes),
// overlapped across co-resident blocks (m114).
// Kept from R8 (verified): 4-term exact-pair product; BM=128 2-barrier
// loop (R7: BM=64 worse); both-sides LDS swizzle; per-wave plg epilogue.
#define BM 128
#define BN 64
#define BK 32
#define NSLICE 32             // (HH/BN) * 2 wn-waves
__global__ __launch_bounds__(256) void k_gemm_mfma(
    const unsigned short* __restrict__ Xh, const unsigned short* __restrict__ Xm,
    const unsigned short* __restrict__ Wh, const unsigned short* __restrict__ Wm,
    const float* __restrict__ b1, const float* __restrict__ w2,
    float* __restrict__ plg,
    const float* __restrict__ hc_raw, const float* __restrict__ bc1,
    const float* __restrict__ wc2, const float* __restrict__ bc2,
    float* __restrict__ adj) {
  __shared__ unsigned short As[2][BM * BK];   // 16KB
  __shared__ unsigned short Bs[2][BN * BK];   // 8KB
  __shared__ float b1s[BN];
  __shared__ float w2s[BN * 9];               // padded stride 9
  __shared__ float red[4][EE];
  int tid = threadIdx.x;

  if (blockIdx.y == HH / BN) {   // adj blocks
    if (blockIdx.x >= BB) return;
    int b = blockIdx.x;
    float part[EE] = {};
    for (int j = tid; j < HH; j += 256) {
      float v = fmaxf(hc_raw[b * HH + j] + bc1[j], 0.f);
      for (int e = 0; e < EE; ++e) part[e] += v * wc2[j * EE + e];
    }
    for (int m = 1; m < 64; m <<= 1)
      for (int e = 0; e < EE; ++e) part[e] += __shfl_xor(part[e], m);
    int wave = tid >> 6, lane = tid & 63;
    if (lane == 0)
      for (int e = 0; e < EE; ++e) red[wave][e] = part[e];
    __syncthreads();
    if (tid < EE) {
      float s = bc2[tid];
      for (int w = 0; w < 4; ++w) s += red[w][tid];
      adj[b * EE + tid] = tanhf(s);
    }
    return;
  }

  int m0 = blockIdx.x * BM, n0 = blockIdx.y * BN;
  if (tid < BN) b1s[tid] = b1[n0 + tid];
#pragma unroll
  for (int rdx = 0; rdx < 2; ++rdx) {  // stage w2 tile: 64x8
    int i = tid + rdx * 256;
    int c = i >> 3, e = i & 7;
    w2s[c * 9 + e] = w2[(size_t)(n0 + c) * EE + e];
  }

  int lane = tid & 63, wave = tid >> 6;
  int wm = wave & 1, wn = wave >> 1;   // wave tile: 64 rows x 32 cols
  int q = lane >> 4, mr = lane & 15;
  // staging: row-within-group; k-quarter pre-swizzled at the GLOBAL source
  // (LDS dest stays linear for global_load_lds); same involution on read.
  int lr = lane >> 2;
  int lqs = (lane & 3) ^ ((lane >> 3) & 3);
  int qsw = (q ^ ((mr >> 1) & 3)) * 8;

  f32x4 acc[4][2] = {};
  const unsigned short* Ag[2] = {Xh, Xm};
  const unsigned short* Bg[2] = {Wh, Wm};

  for (int k0 = 0; k0 < HH; k0 += BK) {
    __syncthreads();
    // A: 16 wave-instrs (2 planes x 8 groups of 16 rows); this wave does 4
#pragma unroll
    for (int j = 0; j < 4; ++j) {
      int i = wave + 4 * j;
      int s = i >> 3, g = i & 7;
      gload_lds16(Ag[s] + (size_t)(m0 + g * 16 + lr) * HH + k0 + lqs * 8,
                  &As[s][g * 512]);
    }
    // B: 8 wave-instrs (2 planes x 4 groups of 16 rows); this wave does 2
#pragma unroll
    for (int j = 0; j < 2; ++j) {
      int i = wave + 4 * j;
      int s = i >> 2, g = i & 3;
      gload_lds16(Bg[s] + (size_t)(n0 + g * 16 + lr) * HH + k0 + lqs * 8,
                  &Bs[s][g * 512]);
    }
    __syncthreads();

    short8 af[2][4], bv[2][2];
#pragma unroll
    for (int s = 0; s < 2; ++s) {
#pragma unroll
      for (int mi = 0; mi < 4; ++mi)
        af[s][mi] = *(const short8*)&As[s][(wm * 4 + mi) * 512 + mr * 32 + qsw];
#pragma unroll
      for (int ni = 0; ni < 2; ++ni)
        bv[s][ni] = *(const short8*)&Bs[s][(wn * 2 + ni) * 512 + mr * 32 + qsw];
    }
#pragma unroll
    for (int mi = 0; mi < 4; ++mi)
#pragma unroll
      for (int ni = 0; ni < 2; ++ni) {
        f32x4 c = acc[mi][ni];
        c = __builtin_amdgcn_mfma_f32_16x16x32_bf16(af[0][mi], bv[0][ni], c, 0, 0, 0); // h.h
        c = __builtin_amdgcn_mfma_f32_16x16x32_bf16(af[0][mi], bv[1][ni], c, 0, 0, 0); // h.m
        c = __builtin_amdgcn_mfma_f32_16x16x32_bf16(af[1][mi], bv[0][ni], c, 0, 0, 0); // m.h
        c = __builtin_amdgcn_mfma_f32_16x16x32_bf16(af[1][mi], bv[1][ni], c, 0, 0, 0); // m.m
        acc[mi][ni] = c;
      }
  }

  // epilogue: relu(+b1), then this wave's partial logits over its 32 cols.
  // lane holds rows (wm*64+mi*16+q*4+r), cols c0=wn*32+mr, c1=c0+16.
  // shfl_xor m<16 reduces over mr; mr==0 lane stores 8 floats.
  // slice = blockIdx.y*2 + wn: each (row, slice) written by exactly one lane.
  int slice = blockIdx.y * 2 + wn;   // 0..31
#pragma unroll
  for (int mi = 0; mi < 4; ++mi)
#pragma unroll
    for (int r = 0; r < 4; ++r) {
      int rowl = wm * 64 + mi * 16 + q * 4 + r;
      int c0 = wn * 32 + mr, c1 = c0 + 16;
      float v0 = fmaxf(acc[mi][0][r] + b1s[c0], 0.f);
      float v1 = fmaxf(acc[mi][1][r] + b1s[c1], 0.f);
      float pe[EE];
#pragma unroll
      for (int e = 0; e < EE; ++e)
        pe[e] = v0 * w2s[c0 * 9 + e] + v1 * w2s[c1 * 9 + e];
#pragma unroll
      for (int m = 1; m < 16; m <<= 1)
#pragma unroll
        for (int e = 0; e < EE; ++e) pe[e] += __shfl_xor(pe[e], m);
      if (mr == 0) {
        float* lp = &plg[((size_t)slice * NTOK + (m0 + rowl)) * EE];
        float4 pa = {pe[0], pe[1], pe[2], pe[3]};
        float4 pb = {pe[4], pe[5], pe[6], pe[7]};
        *(float4*)lp = pa;
        *(float4*)(lp + 4) = pb;
      }
    }
}

// ---------------- D4: sum plg slices + softmax + top2 + psum ------------
// 16 blocks x 256 threads, one token per thread. Reads the 32 partial-logit
// slices (4MB, coalesced 32B/thread/slice), finishes logits with b2+adj,
// then softmax / top-2 / normalization / psum.
__global__ __launch_bounds__(256) void k_logits2(
    const float* __restrict__ plg, const float* __restrict__ b2,
    const float* __restrict__ adj, float* __restrict__ probs_out,
    int* __restrict__ idx_pack, float* __restrict__ p1o, float* __restrict__ p2o,
    float* __restrict__ psum) {
  __shared__ float ps[EE];
  int tid = threadIdx.x;
  if (tid < EE) ps[tid] = 0.f;
  __syncthreads();
  int t = blockIdx.x * 256 + tid;
  int b = t >> 11;
  float l[EE] = {};
#pragma unroll
  for (int s = 0; s < NSLICE; ++s) {
    const float* pp = &plg[((size_t)s * NTOK + t) * EE];
    float4 a = *(const float4*)pp;
    float4 c = *(const float4*)(pp + 4);
    l[0] += a.x; l[1] += a.y; l[2] += a.z; l[3] += a.w;
    l[4] += c.x; l[5] += c.y; l[6] += c.z; l[7] += c.w;
  }
  float mx = -1e30f;
#pragma unroll
  for (int e = 0; e < EE; ++e) {
    l[e] += b2[e] + adj[b * EE + e];
    mx = fmaxf(mx, l[e]);
  }
  float s = 0.f;
#pragma unroll
  for (int e = 0; e < EE; ++e) { l[e] = expf(l[e] - mx); s += l[e]; }
  float inv = 1.f / s;
#pragma unroll
  for (int e = 0; e < EE; ++e) l[e] *= inv;
  float4 pa = {l[0], l[1], l[2], l[3]}, pb = {l[4], l[5], l[6], l[7]};
  *(float4*)&probs_out[(size_t)t * EE] = pa;
  *(float4*)&probs_out[(size_t)t * EE + 4] = pb;
  int e1 = 0; float p1 = l[0];
#pragma unroll
  for (int e = 1; e < EE; ++e) if (l[e] > p1) { p1 = l[e]; e1 = e; }
  int e2 = -1; float p2 = -1.f;
#pragma unroll
  for (int e = 0; e < EE; ++e) if (e != e1 && l[e] > p2) { p2 = l[e]; e2 = e; }
  float norm = 1.f / (p1 + p2 + 1e-8f);
  idx_pack[t] = e1 | (e2 << 8);
  p1o[t] = p1 * norm;
  p2o[t] = p2 * norm;
#pragma unroll
  for (int m = 1; m < 64; m <<= 1)
#pragma unroll
    for (int e = 0; e < EE; ++e) l[e] += __shfl_xor(l[e], m);
  if ((tid & 63) == 0)
#pragma unroll
    for (int e = 0; e < EE; ++e) atomicAdd(&ps[e], l[e]);
  __syncthreads();
  if (tid < EE) atomicAdd(&psum[tid], ps[tid]);
}

// ---------------- fp32 fallback GEMM (+ old softmax path) ----------------
__global__ __launch_bounds__(256) void k_gemm_f32(
    const float* __restrict__ X, const float* __restrict__ w1,
    const float* __restrict__ b1, const float* __restrict__ w2,
    float* __restrict__ logits) {
  __shared__ float Asf[16][65];
  __shared__ float Bsf[16][64];
  __shared__ float w2sf[64][EE];
  int tid = threadIdx.x;
  int m0 = blockIdx.x * 64, n0 = blockIdx.y * 64;
  for (int i = tid; i < 64 * EE; i += 256)
    w2sf[i / EE][i % EE] = w2[(size_t)(n0 + i / EE) * EE + (i % EE)];
  float acc[4][4] = {};
  int tx = tid & 15, ty = tid >> 4;
  for (int k0 = 0; k0 < HH; k0 += 16) {
    for (int idx = tid; idx < 64 * 16; idx += 256) {
      int m = idx >> 4, kk = idx & 15;
      Asf[kk][m] = X[(size_t)(m0 + m) * HH + k0 + kk];
    }
    for (int idx = tid; idx < 16 * 64; idx += 256) {
      int kk = idx >> 6, n = idx & 63;
      Bsf[kk][n] = w1[(size_t)(k0 + kk) * HH + n0 + n];
    }
    __syncthreads();
    for (int kk = 0; kk < 16; ++kk) {
      float a[4], bb[4];
      for (int i = 0; i < 4; ++i) a[i] = Asf[kk][ty * 4 + i];
      for (int j = 0; j < 4; ++j) bb[j] = Bsf[kk][tx * 4 + j];
      for (int i = 0; i < 4; ++i)
        for (int j = 0; j < 4; ++j) acc[i][j] += a[i] * bb[j];
    }
    __syncthreads();
  }
  float p[4][EE] = {};
  for (int i = 0; i < 4; ++i)
    for (int j = 0; j < 4; ++j) {
      int c = tx * 4 + j;
      float v = fmaxf(acc[i][j] + b1[n0 + c], 0.f);
      for (int e = 0; e < EE; ++e) p[i][e] += v * w2sf[c][e];
    }
  for (int m = 1; m < 16; m <<= 1)
    for (int i = 0; i < 4; ++i)
      for (int e = 0; e < EE; ++e) p[i][e] += __shfl_xor(p[i][e], m);
  if (tx == 0)
    for (int i = 0; i < 4; ++i)
      for (int e = 0; e < EE; ++e)
        atomicAdd(&logits[(size_t)(m0 + ty * 4 + i) * EE + e], p[i][e]);
}

__global__ void k_init_logits(const float* __restrict__ adj, const float* __restrict__ b2,
                              float* __restrict__ logits) {
  int i = blockIdx.x * 256 + threadIdx.x;
  int e = i & 7;
  int t = i >> 3;
  int b = t >> 11;
  logits[i] = b2[e] + adj[b * EE + e];
}

__global__ void k_softmax(const float* __restrict__ logits, float* __restrict__ probs_out,
                          int* __restrict__ idx_pack, float* __restrict__ p1o,
                          float* __restrict__ p2o, float* __restrict__ psum) {
  int t = blockIdx.x * 256 + threadIdx.x;
  float l[EE];
  float mx = -1e30f;
  for (int e = 0; e < EE; ++e) { l[e] = logits[t * EE + e]; mx = fmaxf(mx, l[e]); }
  float s = 0.f;
  for (int e = 0; e < EE; ++e) { l[e] = expf(l[e] - mx); s += l[e]; }
  float inv = 1.f / s;
  for (int e = 0; e < EE; ++e) { l[e] *= inv; probs_out[t * EE + e] = l[e]; }
  int e1 = 0; float p1 = l[0];
  for (int e = 1; e < EE; ++e) if (l[e] > p1) { p1 = l[e]; e1 = e; }
  int e2 = -1; float p2 = -1.f;
  for (int e = 0; e < EE; ++e) if (e != e1 && l[e] > p2) { p2 = l[e]; e2 = e; }
  float norm = 1.f / (p1 + p2 + 1e-8f);
  idx_pack[t] = e1 | (e2 << 8);
  p1o[t] = p1 * norm;
  p2o[t] = p2 * norm;
  for (int m = 1; m < 64; m <<= 1)
    for (int e = 0; e < EE; ++e) l[e] += __shfl_xor(l[e], m);
  if ((threadIdx.x & 63) == 0)
    for (int e = 0; e < EE; ++e) atomicAdd(&psum[e], l[e]);
}

__global__ __launch_bounds__(256) void k_route(
    const int* __restrict__ idx_pack, const float* __restrict__ p1,
    const float* __restrict__ p2, const float* __restrict__ psum,
    float* __restrict__ disp, float* __restrict__ comb, float* __restrict__ aux_out) {
  __shared__ int cnt[256][EE];
  __shared__ int tot[EE];
  int tid = threadIdx.x;
  const int CH = NASSIGN / 256;
  int n0 = tid * CH;
  int local[EE] = {};
  for (int n = n0; n < n0 + CH; ++n) {
    int t = n >> 1;
    int pk = idx_pack[t];
    int e = (n & 1) ? (pk >> 8) : (pk & 0xff);
    local[e]++;
  }
  for (int e = 0; e < EE; ++e) cnt[tid][e] = local[e];
  __syncthreads();
  if (tid < EE) {
    int run = 0;
    for (int t = 0; t < 256; ++t) { int v = cnt[t][tid]; cnt[t][tid] = run; run += v; }
    tot[tid] = run;
  }
  __syncthreads();
  int off[EE];
  for (int e = 0; e < EE; ++e) off[e] = cnt[tid][e];
  for (int n = n0; n < n0 + CH; ++n) {
    int t = n >> 1;
    int pk = idx_pack[t];
    int e; float p;
    if (n & 1) { e = pk >> 8; p = p2[t]; } else { e = pk & 0xff; p = p1[t]; }
    int pos = off[e]++;
    if (pos < CAP) {
      size_t o = (size_t)t * EE * CAP + (size_t)e * CAP + pos;
      disp[o] = 1.0f;
      comb[o] = p;
    }
  }
  if (tid == 0) {
    float aux = 0.f;
    for (int e = 0; e < EE; ++e)
      aux += (psum[e] / (float)NTOK) * ((float)tot[e] / (float)NASSIGN);
    aux_out[0] = aux * (float)EE;
  }
}

extern "C" void kernel_launch(void* const* d_in, const int* in_sizes, int n_in,
                              void* d_out, int out_size, void* d_ws, size_t ws_size,
                              hipStream_t stream) {
  const float* x   = (const float*)d_in[0];
  const float* w1  = (const float*)d_in[1];
  const float* b1  = (const float*)d_in[2];
  const float* w2  = (const float*)d_in[3];
  const float* b2  = (const float*)d_in[4];
  const float* wc1 = (const float*)d_in[5];
  const float* bc1 = (const float*)d_in[6];
  const float* wc2 = (const float*)d_in[7];
  const float* bc2 = (const float*)d_in[8];
  const float* chr = (const float*)d_in[9];

  float* out = (float*)d_out;
  float* disp  = out;
  float* comb  = disp + (size_t)NTOK * EE * CAP;
  float* probs = comb + (size_t)NTOK * EE * CAP;
  float* aux   = probs + (size_t)NTOK * EE;

  float* ws = (float*)d_ws;
  float* psum   = ws + WS_PSUM;
  float* hcr    = ws + WS_HC;
  float* adj    = ws + WS_ADJ;
  float* p1     = ws + WS_P1;
  float* p2     = ws + WS_P2;
  int*   idxp   = (int*)(ws + WS_IDX);
  float* logits = ws + WS_LOGITS;           // fallback only
  float* avgp   = ws + WS_LOGITS;           // avg partials (mfma + fallback pre-gemm)

  char* wsb = (char*)d_ws;
  unsigned short* Xh = (unsigned short*)(wsb + WS_BF16_BYTE);
  unsigned short* Xm = Xh + (size_t)NTOK * HH;
  unsigned short* Wh = Xm + (size_t)NTOK * HH;
  unsigned short* Wm = Wh + (size_t)HH * HH;
  float* plg = (float*)(wsb + WS_H_BYTE);   // partial logits [32][4096][8]

  bool use_mfma = ws_size >= WS_NEED;

  if (use_mfma) {
    // D1: prep_x + prep_w (2-plane split) + avg partials + ws-head zero
    //     + full 403MB disp/comb zero-stream (moved out of the GEMM)
    k_prep<<<PREPX_BLKS + PREPW_BLKS + AVG_BLKS, 256, 0, stream>>>(
        x, w1, Xh, Xm, Wh, Wm, ws, avgp, (f32x4*)d_out);
    // D2: hc (atomics into hc_raw zeroed in D1)
    k_hc<<<dim3(HH / 256, 8, BB), 256, 0, stream>>>(avgp, chr, wc1, hcr);
    // D3: 512 GEMM blocks (4-term, pure compute loop; plg epilogue) + 2 adj
    k_gemm_mfma<<<dim3(NTOK / BM, HH / BN + 1), 256, 0, stream>>>(
        Xh, Xm, Wh, Wm, b1, w2, plg, hcr, bc1, wc2, bc2, adj);
    // D4: slice-sum + softmax + top2 + psum (16 blocks)
    k_logits2<<<NTOK / 256, 256, 0, stream>>>(plg, b2, adj, probs, idxp, p1, p2, psum);
  } else {
    hipMemsetAsync(d_ws, 0, WS_ZERO_BYTES, stream);
    hipMemsetAsync(d_out, 0, (size_t)out_size * sizeof(float), stream);
    k_avgp<<<dim3(HH / 256, 16, BB), 256, 0, stream>>>(x, avgp);
    k_hc<<<dim3(HH / 256, 8, BB), 256, 0, stream>>>(avgp, chr, wc1, hcr);
    k_adj<<<BB, 256, 0, stream>>>(hcr, bc1, wc2, bc2, adj);
    k_init_logits<<<(NTOK * EE) / 256, 256, 0, stream>>>(adj, b2, logits);
    k_gemm_f32<<<dim3(NTOK / 64, HH / 64), 256, 0, stream>>>(x, w1, b1, w2, logits);
    k_softmax<<<NTOK / 256, 256, 0, stream>>>(logits, probs, idxp, p1, p2, psum);
  }
  // D5: serial-order capacity + scatter + aux
  k_route<<<1, 256, 0, stream>>>(idxp, p1, p2, psum, disp, comb, aux);
}

// Round 10
// 491.558 us; speedup vs baseline: 1.0961x; 1.0961x over previous
//
#include <hip/hip_runtime.h>
#include <hip/hip_bf16.h>

#define BB 2
#define SS 2048
#define HH 1024
#define EE 8
#define KK 2
#define CAP 1536
#define NTOK (BB * SS)        // 4096
#define NASSIGN (NTOK * KK)   // 8192

// ---------------- workspace layout (float indices) ----------------
#define WS_PSUM   0            // 8
#define WS_AVG    8            // 2048  (fallback path full sums; unused in mfma path)
#define WS_HC     2056         // 2048  (raw pre-bias pre-relu, atomic target)
#define WS_ADJ    4104         // 16
#define WS_P1     4120         // 4096
#define WS_P2     8216         // 4096
#define WS_IDX    12312        // 4096 ints
#define WS_LOGITS 16408        // 32768: fallback logits OR avg partials (16*2*1024)
#define WS_ZERO_FLOATS 4112    // psum+avg+hc+adj head (zeroed by prep blk0 / memset)
#define WS_ZERO_BYTES 16448
#define WS_BF16_BYTE 196704    // bf16 planes start here (16B aligned)
// planes (4-term): Xh/Xm 2*8388608 B + Wh/Wm 2*2097152 B = 20971520 B
#define WS_H_BYTE (WS_BF16_BYTE + 31457280)   // plg partial logits (4MB used)
#define WS_NEED (WS_H_BYTE + 16777216ull)

using short8 = __attribute__((ext_vector_type(8))) short;
using u16x8  = __attribute__((ext_vector_type(8))) unsigned short;
using f32x4  = __attribute__((ext_vector_type(4))) float;

// ---- bf16 split helpers (manual RNE) ----
__device__ __forceinline__ unsigned short f2bf(float f) {
  unsigned u = __float_as_uint(f);
  unsigned r = (u + 0x7fffu + ((u >> 16) & 1u)) >> 16;
  return (unsigned short)r;
}
__device__ __forceinline__ float bf2f(unsigned short h) {
  return __uint_as_float((unsigned)h << 16);
}
// 2-way split: x ~= h + m with |x-(h+m)| <= 2^-17|x| (double-bf16).
__device__ __forceinline__ void split2(float x, unsigned short& h,
                                       unsigned short& m) {
  h = f2bf(x);
  m = f2bf(x - bf2f(h));
}

// async global->LDS, 16B per lane; lptr is wave-uniform base, HW adds lane*16
__device__ __forceinline__ void gload_lds16(const void* g, void* l) {
  __builtin_amdgcn_global_load_lds(
      (const __attribute__((address_space(1))) void*)g,
      (__attribute__((address_space(3))) void*)l, 16, 0, 0);
}

// ---------------- D1: consolidated prep dispatch (R8 form) ---------------
// blocks [0,4096): split X -> 2 bf16 planes (blk0 also zeros ws scalar head)
// blocks [4096,4352): split+transpose w1 -> 2 bf16 planes
// blocks [4352,4480): avg partial sums (no atomics, no zero-init needed)
#define PREPX_BLKS 4096
#define PREPW_BLKS 256
#define AVG_BLKS   128
__global__ __launch_bounds__(256) void k_prep(
    const float* __restrict__ x, const float* __restrict__ w1,
    unsigned short* __restrict__ Xh, unsigned short* __restrict__ Xm,
    unsigned short* __restrict__ Wh, unsigned short* __restrict__ Wm,
    float* __restrict__ wshead, float* __restrict__ avg_part) {
  __shared__ unsigned short Th[64 * 65], Tm[64 * 65];
  int tid = threadIdx.x;
  int bid = blockIdx.x;
  if (bid < PREPX_BLKS) {
    if (bid == 0)
      for (int j = tid; j < WS_ZERO_FLOATS; j += 256) wshead[j] = 0.f;
    int i = (bid * 256 + tid) * 4;
    float4 v = *(const float4*)&x[i];
    unsigned short h[4], m[4];
    split2(v.x, h[0], m[0]);
    split2(v.y, h[1], m[1]);
    split2(v.z, h[2], m[2]);
    split2(v.w, h[3], m[3]);
    *(ushort4*)&Xh[i] = make_ushort4(h[0], h[1], h[2], h[3]);
    *(ushort4*)&Xm[i] = make_ushort4(m[0], m[1], m[2], m[3]);
  } else if (bid < PREPX_BLKS + PREPW_BLKS) {
    int pid = bid - PREPX_BLKS;
    int k0 = (pid & 15) * 64, n0 = (pid >> 4) * 64;
    for (int i = 0; i < 16; ++i) {
      int e = i * 256 + tid;
      int k = e >> 6, n = e & 63;
      float v = w1[(size_t)(k0 + k) * HH + n0 + n];
      unsigned short h, m;
      split2(v, h, m);
      Th[n * 65 + k] = h; Tm[n * 65 + k] = m;
    }
    __syncthreads();
    for (int i = 0; i < 16; ++i) {
      int e = i * 256 + tid;
      int n = e >> 6, k = e & 63;
      size_t o = (size_t)(n0 + n) * HH + k0 + k;
      Wh[o] = Th[n * 65 + k]; Wm[o] = Tm[n * 65 + k];
    }
  } else {
    int pid = bid - PREPX_BLKS - PREPW_BLKS;  // 0..127
    int h = (pid & 3) * 256 + tid;
    int c = (pid >> 2) & 15;
    int b = pid >> 6;
    const float* p = x + (size_t)b * SS * HH + (size_t)(c * 128) * HH + h;
    float s = 0.f;
    for (int i = 0; i < 128; ++i) s += p[(size_t)i * HH];
    avg_part[(c * BB + b) * HH + h] = s;   // raw partial sum
  }
}

// standalone avg-partials kernel (fallback path only)
__global__ void k_avgp(const float* __restrict__ x, float* __restrict__ avg_part) {
  int h = blockIdx.x * 256 + threadIdx.x;
  int c = blockIdx.y;
  int b = blockIdx.z;
  const float* p = x + (size_t)b * SS * HH + (size_t)(c * 128) * HH + h;
  float s = 0.f;
  for (int i = 0; i < 128; ++i) s += p[(size_t)i * HH];
  avg_part[(c * BB + b) * HH + h] = s;
}

// hc_raw += partial dot over i-chunk; reduces the 16 avg partials through LDS
__global__ void k_hc(const float* __restrict__ avg_part, const float* __restrict__ chr,
                     const float* __restrict__ wc1, float* __restrict__ hc_raw) {
  __shared__ float avg_s[128];
  int tid = threadIdx.x;
  int j = blockIdx.x * 256 + tid;
  int c = blockIdx.y;
  int b = blockIdx.z;
  if (tid < 128) {
    float s = 0.f;
    for (int cc = 0; cc < 16; ++cc)
      s += avg_part[(cc * BB + b) * HH + c * 128 + tid];
    avg_s[tid] = s * (1.0f / SS);
  }
  __syncthreads();
  float acc = 0.f;
  for (int il = 0; il < 128; ++il)
    acc += avg_s[il] * wc1[(size_t)(c * 128 + il) * HH + j];
  if (c == 7)
    for (int i = 0; i < EE; ++i)
      acc += chr[i] * wc1[(size_t)(HH + i) * HH + j];
  atomicAdd(&hc_raw[b * HH + j], acc);
}

// standalone adj kernel (fallback path only; mfma path runs adj inside D3)
__global__ void k_adj(const float* __restrict__ hc_raw, const float* __restrict__ bc1,
                      const float* __restrict__ wc2, const float* __restrict__ bc2,
                      float* __restrict__ adj) {
  int b = blockIdx.x;
  int tid = threadIdx.x;
  float part[EE] = {};
  for (int j = tid; j < HH; j += 256) {
    float v = fmaxf(hc_raw[b * HH + j] + bc1[j], 0.f);
    for (int e = 0; e < EE; ++e) part[e] += v * wc2[j * EE + e];
  }
  for (int m = 1; m < 64; m <<= 1)
    for (int e = 0; e < EE; ++e) part[e] += __shfl_xor(part[e], m);
  __shared__ float red[4][EE];
  int wave = tid >> 6, lane = tid & 63;
  if (lane == 0)
    for (int e = 0; e < EE; ++e) red[wave][e] = part[e];
  __syncthreads();
  if (tid < EE) {
    float s = bc2[tid];
    for (int w = 0; w < 4; ++w) s += red[w][tid];
    adj[b * EE + tid] = tanhf(s);
  }
}

// ---------------- D3: MFMA GEMM (R8 anchor; BK 32->64) -------------------
// SINGLE-VARIABLE EXPERIMENT vs R8: BK=64 -> 16 K-iterations instead of 32.
// Each barrier-drain event (vmcnt(0) of staging loads + NT store acks) now
// amortizes 2x the work; R9 isolated this fixed per-event cost as the
// GEMM's dominant term. LDS 27->51KB is harmless: grid (512 blocks = 2/CU)
// is the occupancy cap, not LDS. K-chunk order unchanged (k0 asc, kk asc)
// -> bit-identical numerics to R8.
// Kept from R8 (verified): 4-term exact-pair; in-loop NT zeroing (R9: moving
// it out costs +46us); both-sides LDS swizzle (rederived for 128B rows:
// source quarter lq^lr, read (kk*4+q)^(mr&7) -> 2-way max, free);
// per-wave plg epilogue.
#define BM 128
#define BN 64
#define BK 64
#define NSLICE 32             // (HH/BN) * 2 wn-waves
#define ZF4_PER_BLOCK 49152   // 25165824 f4 (disp+comb) / 512 gemm blocks
__global__ __launch_bounds__(256) void k_gemm_mfma(
    const unsigned short* __restrict__ Xh, const unsigned short* __restrict__ Xm,
    const unsigned short* __restrict__ Wh, const unsigned short* __restrict__ Wm,
    const float* __restrict__ b1, const float* __restrict__ w2,
    float* __restrict__ plg,
    f32x4* __restrict__ zout,
    const float* __restrict__ hc_raw, const float* __restrict__ bc1,
    const float* __restrict__ wc2, const float* __restrict__ bc2,
    float* __restrict__ adj) {
  __shared__ unsigned short As[2][BM * BK];   // 32KB (2 planes x 128x64)
  __shared__ unsigned short Bs[2][BN * BK];   // 16KB
  __shared__ float b1s[BN];
  __shared__ float w2s[BN * 9];               // padded stride 9
  __shared__ float red[4][EE];
  int tid = threadIdx.x;

  if (blockIdx.y == HH / BN) {   // adj blocks
    if (blockIdx.x >= BB) return;
    int b = blockIdx.x;
    float part[EE] = {};
    for (int j = tid; j < HH; j += 256) {
      float v = fmaxf(hc_raw[b * HH + j] + bc1[j], 0.f);
      for (int e = 0; e < EE; ++e) part[e] += v * wc2[j * EE + e];
    }
    for (int m = 1; m < 64; m <<= 1)
      for (int e = 0; e < EE; ++e) part[e] += __shfl_xor(part[e], m);
    int wave = tid >> 6, lane = tid & 63;
    if (lane == 0)
      for (int e = 0; e < EE; ++e) red[wave][e] = part[e];
    __syncthreads();
    if (tid < EE) {
      float s = bc2[tid];
      for (int w = 0; w < 4; ++w) s += red[w][tid];
      adj[b * EE + tid] = tanhf(s);
    }
    return;
  }

  int m0 = blockIdx.x * BM, n0 = blockIdx.y * BN;
  if (tid < BN) b1s[tid] = b1[n0 + tid];
#pragma unroll
  for (int rdx = 0; rdx < 2; ++rdx) {  // stage w2 tile: 64x8
    int i = tid + rdx * 256;
    int c = i >> 3, e = i & 7;
    w2s[c * 9 + e] = w2[(size_t)(n0 + c) * EE + e];
  }

  int bid = blockIdx.y * gridDim.x + blockIdx.x;   // 0..511
  f32x4* zp = zout + (size_t)bid * ZF4_PER_BLOCK;
  const f32x4 z4 = {0.f, 0.f, 0.f, 0.f};

  int lane = tid & 63, wave = tid >> 6;
  int wm = wave & 1, wn = wave >> 1;   // wave tile: 64 rows x 32 cols
  int q = lane >> 4, mr = lane & 15;
  // staging for 128B rows: one instr covers 8 rows x 64 cols.
  // lr8 = row within instr block, lq8 = 16B quarter; source quarter
  // pre-swizzled lq8^lr8 (LDS dest stays linear for global_load_lds).
  int lr8 = lane >> 3;
  int lq8 = lane & 7;
  int lqs8 = lq8 ^ lr8;
  int mr7 = mr & 7;   // read-side swizzle key (row within 8-row stripe)

  f32x4 acc[4][2] = {};
  const unsigned short* Ag[2] = {Xh, Xm};
  const unsigned short* Bg[2] = {Wh, Wm};

  for (int k0 = 0; k0 < HH; k0 += BK) {
    __syncthreads();
    // A: 32 wave-instrs (2 planes x 8 groups x 2 half-groups of 8 rows);
    // this wave does 8.
#pragma unroll
    for (int j = 0; j < 8; ++j) {
      int i = wave + 4 * j;          // 0..31
      int s = i >> 4;                // plane
      int rem = i & 15;
      int g = rem >> 1, h = rem & 1; // 16-row group, 8-row half
      gload_lds16(Ag[s] + (size_t)(m0 + g * 16 + h * 8 + lr8) * HH + k0 + lqs8 * 8,
                  &As[s][g * 1024 + h * 512]);
    }
    // B: 16 wave-instrs (2 planes x 4 groups x 2 halves); this wave does 4.
#pragma unroll
    for (int j = 0; j < 4; ++j) {
      int i = wave + 4 * j;          // 0..15
      int s = i >> 3;
      int rem = i & 7;
      int g = rem >> 1, h = rem & 1;
      gload_lds16(Bg[s] + (size_t)(n0 + g * 16 + h * 8 + lr8) * HH + k0 + lqs8 * 8,
                  &Bs[s][g * 1024 + h * 512]);
    }
    __syncthreads();

    // zero-fill slice: 12 NT stores/thread at the top of the compute phase,
    // drain during MFMA (R8 mechanism; R9 proved moving them out costs +46us)
    {
      int ki = k0 >> 6;              // 0..15
      f32x4* zb = zp + ki * (256 * 12) + tid;
#pragma unroll
      for (int j = 0; j < 12; ++j) __builtin_nontemporal_store(z4, &zb[j * 256]);
    }

#pragma unroll
    for (int kk = 0; kk < 2; ++kk) {
      short8 af[2][4], bv[2][2];
#pragma unroll
      for (int s = 0; s < 2; ++s) {
#pragma unroll
        for (int mi = 0; mi < 4; ++mi)
          af[s][mi] = *(const short8*)
              &As[s][(wm * 4 + mi) * 1024 + mr * 64 + ((kk * 4 + q) ^ mr7) * 8];
#pragma unroll
        for (int ni = 0; ni < 2; ++ni)
          bv[s][ni] = *(const short8*)
              &Bs[s][(wn * 2 + ni) * 1024 + mr * 64 + ((kk * 4 + q) ^ mr7) * 8];
      }
#pragma unroll
      for (int mi = 0; mi < 4; ++mi)
#pragma unroll
        for (int ni = 0; ni < 2; ++ni) {
          f32x4 c = acc[mi][ni];
          c = __builtin_amdgcn_mfma_f32_16x16x32_bf16(af[0][mi], bv[0][ni], c, 0, 0, 0); // h.h
          c = __builtin_amdgcn_mfma_f32_16x16x32_bf16(af[0][mi], bv[1][ni], c, 0, 0, 0); // h.m
          c = __builtin_amdgcn_mfma_f32_16x16x32_bf16(af[1][mi], bv[0][ni], c, 0, 0, 0); // m.h
          c = __builtin_amdgcn_mfma_f32_16x16x32_bf16(af[1][mi], bv[1][ni], c, 0, 0, 0); // m.m
          acc[mi][ni] = c;
        }
    }
  }

  // epilogue: relu(+b1), then this wave's partial logits over its 32 cols.
  // lane holds rows (wm*64+mi*16+q*4+r), cols c0=wn*32+mr, c1=c0+16.
  // shfl_xor m<16 reduces over mr; mr==0 lane stores 8 floats.
  // slice = blockIdx.y*2 + wn: each (row, slice) written by exactly one lane.
  int slice = blockIdx.y * 2 + wn;   // 0..31
#pragma unroll
  for (int mi = 0; mi < 4; ++mi)
#pragma unroll
    for (int r = 0; r < 4; ++r) {
      int rowl = wm * 64 + mi * 16 + q * 4 + r;
      int c0 = wn * 32 + mr, c1 = c0 + 16;
      float v0 = fmaxf(acc[mi][0][r] + b1s[c0], 0.f);
      float v1 = fmaxf(acc[mi][1][r] + b1s[c1], 0.f);
      float pe[EE];
#pragma unroll
      for (int e = 0; e < EE; ++e)
        pe[e] = v0 * w2s[c0 * 9 + e] + v1 * w2s[c1 * 9 + e];
#pragma unroll
      for (int m = 1; m < 16; m <<= 1)
#pragma unroll
        for (int e = 0; e < EE; ++e) pe[e] += __shfl_xor(pe[e], m);
      if (mr == 0) {
        float* lp = &plg[((size_t)slice * NTOK + (m0 + rowl)) * EE];
        float4 pa = {pe[0], pe[1], pe[2], pe[3]};
        float4 pb = {pe[4], pe[5], pe[6], pe[7]};
        *(float4*)lp = pa;
        *(float4*)(lp + 4) = pb;
      }
    }
}

// ---------------- D4: sum plg slices + softmax + top2 + psum ------------
// 16 blocks x 256 threads, one token per thread. Reads the 32 partial-logit
// slices (4MB, coalesced 32B/thread/slice), finishes logits with b2+adj,
// then softmax / top-2 / normalization / psum.
__global__ __launch_bounds__(256) void k_logits2(
    const float* __restrict__ plg, const float* __restrict__ b2,
    const float* __restrict__ adj, float* __restrict__ probs_out,
    int* __restrict__ idx_pack, float* __restrict__ p1o, float* __restrict__ p2o,
    float* __restrict__ psum) {
  __shared__ float ps[EE];
  int tid = threadIdx.x;
  if (tid < EE) ps[tid] = 0.f;
  __syncthreads();
  int t = blockIdx.x * 256 + tid;
  int b = t >> 11;
  float l[EE] = {};
#pragma unroll
  for (int s = 0; s < NSLICE; ++s) {
    const float* pp = &plg[((size_t)s * NTOK + t) * EE];
    float4 a = *(const float4*)pp;
    float4 c = *(const float4*)(pp + 4);
    l[0] += a.x; l[1] += a.y; l[2] += a.z; l[3] += a.w;
    l[4] += c.x; l[5] += c.y; l[6] += c.z; l[7] += c.w;
  }
  float mx = -1e30f;
#pragma unroll
  for (int e = 0; e < EE; ++e) {
    l[e] += b2[e] + adj[b * EE + e];
    mx = fmaxf(mx, l[e]);
  }
  float s = 0.f;
#pragma unroll
  for (int e = 0; e < EE; ++e) { l[e] = expf(l[e] - mx); s += l[e]; }
  float inv = 1.f / s;
#pragma unroll
  for (int e = 0; e < EE; ++e) l[e] *= inv;
  float4 pa = {l[0], l[1], l[2], l[3]}, pb = {l[4], l[5], l[6], l[7]};
  *(float4*)&probs_out[(size_t)t * EE] = pa;
  *(float4*)&probs_out[(size_t)t * EE + 4] = pb;
  int e1 = 0; float p1 = l[0];
#pragma unroll
  for (int e = 1; e < EE; ++e) if (l[e] > p1) { p1 = l[e]; e1 = e; }
  int e2 = -1; float p2 = -1.f;
#pragma unroll
  for (int e = 0; e < EE; ++e) if (e != e1 && l[e] > p2) { p2 = l[e]; e2 = e; }
  float norm = 1.f / (p1 + p2 + 1e-8f);
  idx_pack[t] = e1 | (e2 << 8);
  p1o[t] = p1 * norm;
  p2o[t] = p2 * norm;
#pragma unroll
  for (int m = 1; m < 64; m <<= 1)
#pragma unroll
    for (int e = 0; e < EE; ++e) l[e] += __shfl_xor(l[e], m);
  if ((tid & 63) == 0)
#pragma unroll
    for (int e = 0; e < EE; ++e) atomicAdd(&ps[e], l[e]);
  __syncthreads();
  if (tid < EE) atomicAdd(&psum[tid], ps[tid]);
}

// ---------------- fp32 fallback GEMM (+ old softmax path) ----------------
__global__ __launch_bounds__(256) void k_gemm_f32(
    const float* __restrict__ X, const float* __restrict__ w1,
    const float* __restrict__ b1, const float* __restrict__ w2,
    float* __restrict__ logits) {
  __shared__ float Asf[16][65];
  __shared__ float Bsf[16][64];
  __shared__ float w2sf[64][EE];
  int tid = threadIdx.x;
  int m0 = blockIdx.x * 64, n0 = blockIdx.y * 64;
  for (int i = tid; i < 64 * EE; i += 256)
    w2sf[i / EE][i % EE] = w2[(size_t)(n0 + i / EE) * EE + (i % EE)];
  float acc[4][4] = {};
  int tx = tid & 15, ty = tid >> 4;
  for (int k0 = 0; k0 < HH; k0 += 16) {
    for (int idx = tid; idx < 64 * 16; idx += 256) {
      int m = idx >> 4, kk = idx & 15;
      Asf[kk][m] = X[(size_t)(m0 + m) * HH + k0 + kk];
    }
    for (int idx = tid; idx < 16 * 64; idx += 256) {
      int kk = idx >> 6, n = idx & 63;
      Bsf[kk][n] = w1[(size_t)(k0 + kk) * HH + n0 + n];
    }
    __syncthreads();
    for (int kk = 0; kk < 16; ++kk) {
      float a[4], bb[4];
      for (int i = 0; i < 4; ++i) a[i] = Asf[kk][ty * 4 + i];
      for (int j = 0; j < 4; ++j) bb[j] = Bsf[kk][tx * 4 + j];
      for (int i = 0; i < 4; ++i)
        for (int j = 0; j < 4; ++j) acc[i][j] += a[i] * bb[j];
    }
    __syncthreads();
  }
  float p[4][EE] = {};
  for (int i = 0; i < 4; ++i)
    for (int j = 0; j < 4; ++j) {
      int c = tx * 4 + j;
      float v = fmaxf(acc[i][j] + b1[n0 + c], 0.f);
      for (int e = 0; e < EE; ++e) p[i][e] += v * w2sf[c][e];
    }
  for (int m = 1; m < 16; m <<= 1)
    for (int i = 0; i < 4; ++i)
      for (int e = 0; e < EE; ++e) p[i][e] += __shfl_xor(p[i][e], m);
  if (tx == 0)
    for (int i = 0; i < 4; ++i)
      for (int e = 0; e < EE; ++e)
        atomicAdd(&logits[(size_t)(m0 + ty * 4 + i) * EE + e], p[i][e]);
}

__global__ void k_init_logits(const float* __restrict__ adj, const float* __restrict__ b2,
                              float* __restrict__ logits) {
  int i = blockIdx.x * 256 + threadIdx.x;
  int e = i & 7;
  int t = i >> 3;
  int b = t >> 11;
  logits[i] = b2[e] + adj[b * EE + e];
}

__global__ void k_softmax(const float* __restrict__ logits, float* __restrict__ probs_out,
                          int* __restrict__ idx_pack, float* __restrict__ p1o,
                          float* __restrict__ p2o, float* __restrict__ psum) {
  int t = blockIdx.x * 256 + threadIdx.x;
  float l[EE];
  float mx = -1e30f;
  for (int e = 0; e < EE; ++e) { l[e] = logits[t * EE + e]; mx = fmaxf(mx, l[e]); }
  float s = 0.f;
  for (int e = 0; e < EE; ++e) { l[e] = expf(l[e] - mx); s += l[e]; }
  float inv = 1.f / s;
  for (int e = 0; e < EE; ++e) { l[e] *= inv; probs_out[t * EE + e] = l[e]; }
  int e1 = 0; float p1 = l[0];
  for (int e = 1; e < EE; ++e) if (l[e] > p1) { p1 = l[e]; e1 = e; }
  int e2 = -1; float p2 = -1.f;
  for (int e = 0; e < EE; ++e) if (e != e1 && l[e] > p2) { p2 = l[e]; e2 = e; }
  float norm = 1.f / (p1 + p2 + 1e-8f);
  idx_pack[t] = e1 | (e2 << 8);
  p1o[t] = p1 * norm;
  p2o[t] = p2 * norm;
  for (int m = 1; m < 64; m <<= 1)
    for (int e = 0; e < EE; ++e) l[e] += __shfl_xor(l[e], m);
  if ((threadIdx.x & 63) == 0)
    for (int e = 0; e < EE; ++e) atomicAdd(&psum[e], l[e]);
}

__global__ __launch_bounds__(256) void k_route(
    const int* __restrict__ idx_pack, const float* __restrict__ p1,
    const float* __restrict__ p2, const float* __restrict__ psum,
    float* __restrict__ disp, float* __restrict__ comb, float* __restrict__ aux_out) {
  __shared__ int cnt[256][EE];
  __shared__ int tot[EE];
  int tid = threadIdx.x;
  const int CH = NASSIGN / 256;
  int n0 = tid * CH;
  int local[EE] = {};
  for (int n = n0; n < n0 + CH; ++n) {
    int t = n >> 1;
    int pk = idx_pack[t];
    int e = (n & 1) ? (pk >> 8) : (pk & 0xff);
    local[e]++;
  }
  for (int e = 0; e < EE; ++e) cnt[tid][e] = local[e];
  __syncthreads();
  if (tid < EE) {
    int run = 0;
    for (int t = 0; t < 256; ++t) { int v = cnt[t][tid]; cnt[t][tid] = run; run += v; }
    tot[tid] = run;
  }
  __syncthreads();
  int off[EE];
  for (int e = 0; e < EE; ++e) off[e] = cnt[tid][e];
  for (int n = n0; n < n0 + CH; ++n) {
    int t = n >> 1;
    int pk = idx_pack[t];
    int e; float p;
    if (n & 1) { e = pk >> 8; p = p2[t]; } else { e = pk & 0xff; p = p1[t]; }
    int pos = off[e]++;
    if (pos < CAP) {
      size_t o = (size_t)t * EE * CAP + (size_t)e * CAP + pos;
      disp[o] = 1.0f;
      comb[o] = p;
    }
  }
  if (tid == 0) {
    float aux = 0.f;
    for (int e = 0; e < EE; ++e)
      aux += (psum[e] / (float)NTOK) * ((float)tot[e] / (float)NASSIGN);
    aux_out[0] = aux * (float)EE;
  }
}

extern "C" void kernel_launch(void* const* d_in, const int* in_sizes, int n_in,
                              void* d_out, int out_size, void* d_ws, size_t ws_size,
                              hipStream_t stream) {
  const float* x   = (const float*)d_in[0];
  const float* w1  = (const float*)d_in[1];
  const float* b1  = (const float*)d_in[2];
  const float* w2  = (const float*)d_in[3];
  const float* b2  = (const float*)d_in[4];
  const float* wc1 = (const float*)d_in[5];
  const float* bc1 = (const float*)d_in[6];
  const float* wc2 = (const float*)d_in[7];
  const float* bc2 = (const float*)d_in[8];
  const float* chr = (const float*)d_in[9];

  float* out = (float*)d_out;
  float* disp  = out;
  float* comb  = disp + (size_t)NTOK * EE * CAP;
  float* probs = comb + (size_t)NTOK * EE * CAP;
  float* aux   = probs + (size_t)NTOK * EE;

  float* ws = (float*)d_ws;
  float* psum   = ws + WS_PSUM;
  float* hcr    = ws + WS_HC;
  float* adj    = ws + WS_ADJ;
  float* p1     = ws + WS_P1;
  float* p2     = ws + WS_P2;
  int*   idxp   = (int*)(ws + WS_IDX);
  float* logits = ws + WS_LOGITS;           // fallback only
  float* avgp   = ws + WS_LOGITS;           // avg partials (mfma + fallback pre-gemm)

  char* wsb = (char*)d_ws;
  unsigned short* Xh = (unsigned short*)(wsb + WS_BF16_BYTE);
  unsigned short* Xm = Xh + (size_t)NTOK * HH;
  unsigned short* Wh = Xm + (size_t)NTOK * HH;
  unsigned short* Wm = Wh + (size_t)HH * HH;
  float* plg = (float*)(wsb + WS_H_BYTE);   // partial logits [32][4096][8]

  bool use_mfma = ws_size >= WS_NEED;

  if (use_mfma) {
    // D1: prep_x + prep_w (2-plane split) + avg partials + ws-head zero
    k_prep<<<PREPX_BLKS + PREPW_BLKS + AVG_BLKS, 256, 0, stream>>>(
        x, w1, Xh, Xm, Wh, Wm, ws, avgp);
    // D2: hc (atomics into hc_raw zeroed in D1)
    k_hc<<<dim3(HH / 256, 8, BB), 256, 0, stream>>>(avgp, chr, wc1, hcr);
    // D3: 512 GEMM blocks (4-term, BK=64, in-loop NT zeroing; plg epilogue)
    //     + 2 adj blocks
    k_gemm_mfma<<<dim3(NTOK / BM, HH / BN + 1), 256, 0, stream>>>(
        Xh, Xm, Wh, Wm, b1, w2, plg, (f32x4*)d_out,
        hcr, bc1, wc2, bc2, adj);
    // D4: slice-sum + softmax + top2 + psum (16 blocks)
    k_logits2<<<NTOK / 256, 256, 0, stream>>>(plg, b2, adj, probs, idxp, p1, p2, psum);
  } else {
    hipMemsetAsync(d_ws, 0, WS_ZERO_BYTES, stream);
    hipMemsetAsync(d_out, 0, (size_t)out_size * sizeof(float), stream);
    k_avgp<<<dim3(HH / 256, 16, BB), 256, 0, stream>>>(x, avgp);
    k_hc<<<dim3(HH / 256, 8, BB), 256, 0, stream>>>(avgp, chr, wc1, hcr);
    k_adj<<<BB, 256, 0, stream>>>(hcr, bc1, wc2, bc2, adj);
    k_init_logits<<<(NTOK * EE) / 256, 256, 0, stream>>>(adj, b2, logits);
    k_gemm_f32<<<dim3(NTOK / 64, HH / 64), 256, 0, stream>>>(x, w1, b1, w2, logits);
    k_softmax<<<NTOK / 256, 256, 0, stream>>>(logits, probs, idxp, p1, p2, psum);
  }
  // D5: serial-order capacity + scatter + aux
  k_route<<<1, 256, 0, stream>>>(idxp, p1, p2, psum, disp, comb, aux);
}

// Round 11
// 476.772 us; speedup vs baseline: 1.1301x; 1.0310x over previous
//
#include <hip/hip_runtime.h>
#include <hip/hip_bf16.h>

#define BB 2
#define SS 2048
#define HH 1024
#define EE 8
#define KK 2
#define CAP 1536
#define NTOK (BB * SS)        // 4096
#define NASSIGN (NTOK * KK)   // 8192

// ---------------- workspace layout (float indices) ----------------
#define WS_PSUM   0            // 8
#define WS_AVG    8            // 2048  (fallback path full sums; unused in mfma path)
#define WS_HC     2056         // 2048  (raw pre-bias pre-relu, atomic target)
#define WS_ADJ    4104         // 16
#define WS_P1     4120         // 4096
#define WS_P2     8216         // 4096
#define WS_IDX    12312        // 4096 ints
#define WS_LOGITS 16408        // 32768: fallback logits OR avg partials (16*2*1024)
#define WS_ZERO_FLOATS 4112    // psum+avg+hc+adj head (zeroed by prep blk0 / memset)
#define WS_ZERO_BYTES 16448
#define WS_BF16_BYTE 196704    // bf16 planes start here (16B aligned)
// planes (4-term): Xh/Xm 2*8388608 B + Wh/Wm 2*2097152 B = 20971520 B
#define WS_H_BYTE (WS_BF16_BYTE + 31457280)   // plg (4MB) + hist (512B)
#define WS_NEED (WS_H_BYTE + 16777216ull)

using short8 = __attribute__((ext_vector_type(8))) short;
using u16x8  = __attribute__((ext_vector_type(8))) unsigned short;
using f32x4  = __attribute__((ext_vector_type(4))) float;

// ---- bf16 split helpers (manual RNE) ----
__device__ __forceinline__ unsigned short f2bf(float f) {
  unsigned u = __float_as_uint(f);
  unsigned r = (u + 0x7fffu + ((u >> 16) & 1u)) >> 16;
  return (unsigned short)r;
}
__device__ __forceinline__ float bf2f(unsigned short h) {
  return __uint_as_float((unsigned)h << 16);
}
// 2-way split: x ~= h + m with |x-(h+m)| <= 2^-17|x| (double-bf16).
__device__ __forceinline__ void split2(float x, unsigned short& h,
                                       unsigned short& m) {
  h = f2bf(x);
  m = f2bf(x - bf2f(h));
}

// async global->LDS, 16B per lane; lptr is wave-uniform base, HW adds lane*16
__device__ __forceinline__ void gload_lds16(const void* g, void* l) {
  __builtin_amdgcn_global_load_lds(
      (const __attribute__((address_space(1))) void*)g,
      (__attribute__((address_space(3))) void*)l, 16, 0, 0);
}

// ---------------- D1: consolidated prep dispatch (R8 form) ---------------
// blocks [0,4096): split X -> 2 bf16 planes (blk0 also zeros ws scalar head)
// blocks [4096,4352): split+transpose w1 -> 2 bf16 planes
// blocks [4352,4480): avg partial sums (no atomics, no zero-init needed)
#define PREPX_BLKS 4096
#define PREPW_BLKS 256
#define AVG_BLKS   128
__global__ __launch_bounds__(256) void k_prep(
    const float* __restrict__ x, const float* __restrict__ w1,
    unsigned short* __restrict__ Xh, unsigned short* __restrict__ Xm,
    unsigned short* __restrict__ Wh, unsigned short* __restrict__ Wm,
    float* __restrict__ wshead, float* __restrict__ avg_part) {
  __shared__ unsigned short Th[64 * 65], Tm[64 * 65];
  int tid = threadIdx.x;
  int bid = blockIdx.x;
  if (bid < PREPX_BLKS) {
    if (bid == 0)
      for (int j = tid; j < WS_ZERO_FLOATS; j += 256) wshead[j] = 0.f;
    int i = (bid * 256 + tid) * 4;
    float4 v = *(const float4*)&x[i];
    unsigned short h[4], m[4];
    split2(v.x, h[0], m[0]);
    split2(v.y, h[1], m[1]);
    split2(v.z, h[2], m[2]);
    split2(v.w, h[3], m[3]);
    *(ushort4*)&Xh[i] = make_ushort4(h[0], h[1], h[2], h[3]);
    *(ushort4*)&Xm[i] = make_ushort4(m[0], m[1], m[2], m[3]);
  } else if (bid < PREPX_BLKS + PREPW_BLKS) {
    int pid = bid - PREPX_BLKS;
    int k0 = (pid & 15) * 64, n0 = (pid >> 4) * 64;
    for (int i = 0; i < 16; ++i) {
      int e = i * 256 + tid;
      int k = e >> 6, n = e & 63;
      float v = w1[(size_t)(k0 + k) * HH + n0 + n];
      unsigned short h, m;
      split2(v, h, m);
      Th[n * 65 + k] = h; Tm[n * 65 + k] = m;
    }
    __syncthreads();
    for (int i = 0; i < 16; ++i) {
      int e = i * 256 + tid;
      int n = e >> 6, k = e & 63;
      size_t o = (size_t)(n0 + n) * HH + k0 + k;
      Wh[o] = Th[n * 65 + k]; Wm[o] = Tm[n * 65 + k];
    }
  } else {
    int pid = bid - PREPX_BLKS - PREPW_BLKS;  // 0..127
    int h = (pid & 3) * 256 + tid;
    int c = (pid >> 2) & 15;
    int b = pid >> 6;
    const float* p = x + (size_t)b * SS * HH + (size_t)(c * 128) * HH + h;
    float s = 0.f;
    for (int i = 0; i < 128; ++i) s += p[(size_t)i * HH];
    avg_part[(c * BB + b) * HH + h] = s;   // raw partial sum
  }
}

// standalone avg-partials kernel (fallback path only)
__global__ void k_avgp(const float* __restrict__ x, float* __restrict__ avg_part) {
  int h = blockIdx.x * 256 + threadIdx.x;
  int c = blockIdx.y;
  int b = blockIdx.z;
  const float* p = x + (size_t)b * SS * HH + (size_t)(c * 128) * HH + h;
  float s = 0.f;
  for (int i = 0; i < 128; ++i) s += p[(size_t)i * HH];
  avg_part[(c * BB + b) * HH + h] = s;
}

// hc_raw += partial dot over i-chunk; reduces the 16 avg partials through LDS
__global__ void k_hc(const float* __restrict__ avg_part, const float* __restrict__ chr,
                     const float* __restrict__ wc1, float* __restrict__ hc_raw) {
  __shared__ float avg_s[128];
  int tid = threadIdx.x;
  int j = blockIdx.x * 256 + tid;
  int c = blockIdx.y;
  int b = blockIdx.z;
  if (tid < 128) {
    float s = 0.f;
    for (int cc = 0; cc < 16; ++cc)
      s += avg_part[(cc * BB + b) * HH + c * 128 + tid];
    avg_s[tid] = s * (1.0f / SS);
  }
  __syncthreads();
  float acc = 0.f;
  for (int il = 0; il < 128; ++il)
    acc += avg_s[il] * wc1[(size_t)(c * 128 + il) * HH + j];
  if (c == 7)
    for (int i = 0; i < EE; ++i)
      acc += chr[i] * wc1[(size_t)(HH + i) * HH + j];
  atomicAdd(&hc_raw[b * HH + j], acc);
}

// standalone adj kernel (fallback path only; mfma path runs adj inside D3)
__global__ void k_adj(const float* __restrict__ hc_raw, const float* __restrict__ bc1,
                      const float* __restrict__ wc2, const float* __restrict__ bc2,
                      float* __restrict__ adj) {
  int b = blockIdx.x;
  int tid = threadIdx.x;
  float part[EE] = {};
  for (int j = tid; j < HH; j += 256) {
    float v = fmaxf(hc_raw[b * HH + j] + bc1[j], 0.f);
    for (int e = 0; e < EE; ++e) part[e] += v * wc2[j * EE + e];
  }
  for (int m = 1; m < 64; m <<= 1)
    for (int e = 0; e < EE; ++e) part[e] += __shfl_xor(part[e], m);
  __shared__ float red[4][EE];
  int wave = tid >> 6, lane = tid & 63;
  if (lane == 0)
    for (int e = 0; e < EE; ++e) red[wave][e] = part[e];
  __syncthreads();
  if (tid < EE) {
    float s = bc2[tid];
    for (int w = 0; w < 4; ++w) s += red[w][tid];
    adj[b * EE + tid] = tanhf(s);
  }
}

// ---------------- D3: MFMA GEMM (R10 form, unchanged) --------------------
// Verified structure: 4-term exact-pair; BM=128/BN=64/BK=64 single-buffered
// 2-barrier loop (dbuf/occupancy/BK/zero-move variants all regressed or
// null, R1-R10); in-loop NT zeroing (R9: moving it out costs +46us);
// both-sides LDS swizzle; per-wave plg epilogue (plain stores, no atomics).
#define BM 128
#define BN 64
#define BK 64
#define NSLICE 32             // (HH/BN) * 2 wn-waves
#define ZF4_PER_BLOCK 49152   // 25165824 f4 (disp+comb) / 512 gemm blocks
__global__ __launch_bounds__(256) void k_gemm_mfma(
    const unsigned short* __restrict__ Xh, const unsigned short* __restrict__ Xm,
    const unsigned short* __restrict__ Wh, const unsigned short* __restrict__ Wm,
    const float* __restrict__ b1, const float* __restrict__ w2,
    float* __restrict__ plg,
    f32x4* __restrict__ zout,
    const float* __restrict__ hc_raw, const float* __restrict__ bc1,
    const float* __restrict__ wc2, const float* __restrict__ bc2,
    float* __restrict__ adj) {
  __shared__ unsigned short As[2][BM * BK];   // 32KB (2 planes x 128x64)
  __shared__ unsigned short Bs[2][BN * BK];   // 16KB
  __shared__ float b1s[BN];
  __shared__ float w2s[BN * 9];               // padded stride 9
  __shared__ float red[4][EE];
  int tid = threadIdx.x;

  if (blockIdx.y == HH / BN) {   // adj blocks
    if (blockIdx.x >= BB) return;
    int b = blockIdx.x;
    float part[EE] = {};
    for (int j = tid; j < HH; j += 256) {
      float v = fmaxf(hc_raw[b * HH + j] + bc1[j], 0.f);
      for (int e = 0; e < EE; ++e) part[e] += v * wc2[j * EE + e];
    }
    for (int m = 1; m < 64; m <<= 1)
      for (int e = 0; e < EE; ++e) part[e] += __shfl_xor(part[e], m);
    int wave = tid >> 6, lane = tid & 63;
    if (lane == 0)
      for (int e = 0; e < EE; ++e) red[wave][e] = part[e];
    __syncthreads();
    if (tid < EE) {
      float s = bc2[tid];
      for (int w = 0; w < 4; ++w) s += red[w][tid];
      adj[b * EE + tid] = tanhf(s);
    }
    return;
  }

  int m0 = blockIdx.x * BM, n0 = blockIdx.y * BN;
  if (tid < BN) b1s[tid] = b1[n0 + tid];
#pragma unroll
  for (int rdx = 0; rdx < 2; ++rdx) {  // stage w2 tile: 64x8
    int i = tid + rdx * 256;
    int c = i >> 3, e = i & 7;
    w2s[c * 9 + e] = w2[(size_t)(n0 + c) * EE + e];
  }

  int bid = blockIdx.y * gridDim.x + blockIdx.x;   // 0..511
  f32x4* zp = zout + (size_t)bid * ZF4_PER_BLOCK;
  const f32x4 z4 = {0.f, 0.f, 0.f, 0.f};

  int lane = tid & 63, wave = tid >> 6;
  int wm = wave & 1, wn = wave >> 1;   // wave tile: 64 rows x 32 cols
  int q = lane >> 4, mr = lane & 15;
  // staging for 128B rows: one instr covers 8 rows x 64 cols.
  // lr8 = row within instr block, lq8 = 16B quarter; source quarter
  // pre-swizzled lq8^lr8 (LDS dest stays linear for global_load_lds).
  int lr8 = lane >> 3;
  int lq8 = lane & 7;
  int lqs8 = lq8 ^ lr8;
  int mr7 = mr & 7;   // read-side swizzle key (row within 8-row stripe)

  f32x4 acc[4][2] = {};
  const unsigned short* Ag[2] = {Xh, Xm};
  const unsigned short* Bg[2] = {Wh, Wm};

  for (int k0 = 0; k0 < HH; k0 += BK) {
    __syncthreads();
    // A: 32 wave-instrs (2 planes x 8 groups x 2 half-groups of 8 rows);
    // this wave does 8.
#pragma unroll
    for (int j = 0; j < 8; ++j) {
      int i = wave + 4 * j;          // 0..31
      int s = i >> 4;                // plane
      int rem = i & 15;
      int g = rem >> 1, h = rem & 1; // 16-row group, 8-row half
      gload_lds16(Ag[s] + (size_t)(m0 + g * 16 + h * 8 + lr8) * HH + k0 + lqs8 * 8,
                  &As[s][g * 1024 + h * 512]);
    }
    // B: 16 wave-instrs (2 planes x 4 groups x 2 halves); this wave does 4.
#pragma unroll
    for (int j = 0; j < 4; ++j) {
      int i = wave + 4 * j;          // 0..15
      int s = i >> 3;
      int rem = i & 7;
      int g = rem >> 1, h = rem & 1;
      gload_lds16(Bg[s] + (size_t)(n0 + g * 16 + h * 8 + lr8) * HH + k0 + lqs8 * 8,
                  &Bs[s][g * 1024 + h * 512]);
    }
    __syncthreads();

    // zero-fill slice: 12 NT stores/thread at the top of the compute phase,
    // drain during MFMA (R8 mechanism; R9 proved moving them out costs +46us)
    {
      int ki = k0 >> 6;              // 0..15
      f32x4* zb = zp + ki * (256 * 12) + tid;
#pragma unroll
      for (int j = 0; j < 12; ++j) __builtin_nontemporal_store(z4, &zb[j * 256]);
    }

#pragma unroll
    for (int kk = 0; kk < 2; ++kk) {
      short8 af[2][4], bv[2][2];
#pragma unroll
      for (int s = 0; s < 2; ++s) {
#pragma unroll
        for (int mi = 0; mi < 4; ++mi)
          af[s][mi] = *(const short8*)
              &As[s][(wm * 4 + mi) * 1024 + mr * 64 + ((kk * 4 + q) ^ mr7) * 8];
#pragma unroll
        for (int ni = 0; ni < 2; ++ni)
          bv[s][ni] = *(const short8*)
              &Bs[s][(wn * 2 + ni) * 1024 + mr * 64 + ((kk * 4 + q) ^ mr7) * 8];
      }
#pragma unroll
      for (int mi = 0; mi < 4; ++mi)
#pragma unroll
        for (int ni = 0; ni < 2; ++ni) {
          f32x4 c = acc[mi][ni];
          c = __builtin_amdgcn_mfma_f32_16x16x32_bf16(af[0][mi], bv[0][ni], c, 0, 0, 0); // h.h
          c = __builtin_amdgcn_mfma_f32_16x16x32_bf16(af[0][mi], bv[1][ni], c, 0, 0, 0); // h.m
          c = __builtin_amdgcn_mfma_f32_16x16x32_bf16(af[1][mi], bv[0][ni], c, 0, 0, 0); // m.h
          c = __builtin_amdgcn_mfma_f32_16x16x32_bf16(af[1][mi], bv[1][ni], c, 0, 0, 0); // m.m
          acc[mi][ni] = c;
        }
    }
  }

  // epilogue: relu(+b1), then this wave's partial logits over its 32 cols.
  // lane holds rows (wm*64+mi*16+q*4+r), cols c0=wn*32+mr, c1=c0+16.
  // shfl_xor m<16 reduces over mr; mr==0 lane stores 8 floats.
  // slice = blockIdx.y*2 + wn: each (row, slice) written by exactly one lane.
  int slice = blockIdx.y * 2 + wn;   // 0..31
#pragma unroll
  for (int mi = 0; mi < 4; ++mi)
#pragma unroll
    for (int r = 0; r < 4; ++r) {
      int rowl = wm * 64 + mi * 16 + q * 4 + r;
      int c0 = wn * 32 + mr, c1 = c0 + 16;
      float v0 = fmaxf(acc[mi][0][r] + b1s[c0], 0.f);
      float v1 = fmaxf(acc[mi][1][r] + b1s[c1], 0.f);
      float pe[EE];
#pragma unroll
      for (int e = 0; e < EE; ++e)
        pe[e] = v0 * w2s[c0 * 9 + e] + v1 * w2s[c1 * 9 + e];
#pragma unroll
      for (int m = 1; m < 16; m <<= 1)
#pragma unroll
        for (int e = 0; e < EE; ++e) pe[e] += __shfl_xor(pe[e], m);
      if (mr == 0) {
        float* lp = &plg[((size_t)slice * NTOK + (m0 + rowl)) * EE];
        float4 pa = {pe[0], pe[1], pe[2], pe[3]};
        float4 pb = {pe[4], pe[5], pe[6], pe[7]};
        *(float4*)lp = pa;
        *(float4*)(lp + 4) = pb;
      }
    }
}

// ---------------- D4: sum plg slices + softmax + top2 + psum + hist -----
// 16 blocks x 256 threads, one token per thread. R11: additionally emits
// per-chunk expert histograms hist[16][8] (LDS atomics) so D5 can run with
// 16 blocks instead of 1.
__global__ __launch_bounds__(256) void k_logits2(
    const float* __restrict__ plg, const float* __restrict__ b2,
    const float* __restrict__ adj, float* __restrict__ probs_out,
    int* __restrict__ idx_pack, float* __restrict__ p1o, float* __restrict__ p2o,
    float* __restrict__ psum, int* __restrict__ hist) {
  __shared__ float ps[EE];
  __shared__ int hs[EE];
  int tid = threadIdx.x;
  if (tid < EE) { ps[tid] = 0.f; hs[tid] = 0; }
  __syncthreads();
  int t = blockIdx.x * 256 + tid;
  int b = t >> 11;
  float l[EE] = {};
#pragma unroll
  for (int s = 0; s < NSLICE; ++s) {
    const float* pp = &plg[((size_t)s * NTOK + t) * EE];
    float4 a = *(const float4*)pp;
    float4 c = *(const float4*)(pp + 4);
    l[0] += a.x; l[1] += a.y; l[2] += a.z; l[3] += a.w;
    l[4] += c.x; l[5] += c.y; l[6] += c.z; l[7] += c.w;
  }
  float mx = -1e30f;
#pragma unroll
  for (int e = 0; e < EE; ++e) {
    l[e] += b2[e] + adj[b * EE + e];
    mx = fmaxf(mx, l[e]);
  }
  float s = 0.f;
#pragma unroll
  for (int e = 0; e < EE; ++e) { l[e] = expf(l[e] - mx); s += l[e]; }
  float inv = 1.f / s;
#pragma unroll
  for (int e = 0; e < EE; ++e) l[e] *= inv;
  float4 pa = {l[0], l[1], l[2], l[3]}, pb = {l[4], l[5], l[6], l[7]};
  *(float4*)&probs_out[(size_t)t * EE] = pa;
  *(float4*)&probs_out[(size_t)t * EE + 4] = pb;
  int e1 = 0; float p1 = l[0];
#pragma unroll
  for (int e = 1; e < EE; ++e) if (l[e] > p1) { p1 = l[e]; e1 = e; }
  int e2 = -1; float p2 = -1.f;
#pragma unroll
  for (int e = 0; e < EE; ++e) if (e != e1 && l[e] > p2) { p2 = l[e]; e2 = e; }
  float norm = 1.f / (p1 + p2 + 1e-8f);
  idx_pack[t] = e1 | (e2 << 8);
  p1o[t] = p1 * norm;
  p2o[t] = p2 * norm;
  atomicAdd(&hs[e1], 1);
  atomicAdd(&hs[e2], 1);
#pragma unroll
  for (int m = 1; m < 64; m <<= 1)
#pragma unroll
    for (int e = 0; e < EE; ++e) l[e] += __shfl_xor(l[e], m);
  if ((tid & 63) == 0)
#pragma unroll
    for (int e = 0; e < EE; ++e) atomicAdd(&ps[e], l[e]);
  __syncthreads();
  if (tid < EE) {
    atomicAdd(&psum[tid], ps[tid]);
    hist[blockIdx.x * EE + tid] = hs[tid];
  }
}

// ---------------- D5: parallel serial-order capacity + scatter + aux -----
// 16 blocks x 256 threads, one token per thread (chunk c = tokens
// [c*256, c*256+256)). Serial (b,s,k) order preserved exactly:
//   pos = base(prior chunks via hist) + scan(prior threads in chunk)
// e1/e2 within a token go to distinct experts -> no within-token term.
__global__ __launch_bounds__(256) void k_route3(
    const int* __restrict__ idx_pack, const float* __restrict__ p1,
    const float* __restrict__ p2, const int* __restrict__ hist,
    const float* __restrict__ psum,
    float* __restrict__ disp, float* __restrict__ comb,
    float* __restrict__ aux_out) {
  __shared__ int cnt[256][EE];
  int tid = threadIdx.x;
  int c = blockIdx.x;
  int t = c * 256 + tid;
  int pk = idx_pack[t];
  int e1 = pk & 0xff, e2 = pk >> 8;
  int local[EE] = {};
  local[e1]++; local[e2]++;
#pragma unroll
  for (int e = 0; e < EE; ++e) cnt[tid][e] = local[e];
  __syncthreads();
  if (tid < EE) {
    int run = 0;
    for (int cc = 0; cc < c; ++cc) run += hist[cc * EE + tid];
    for (int th = 0; th < 256; ++th) {
      int v = cnt[th][tid];
      cnt[th][tid] = run;
      run += v;
    }
  }
  __syncthreads();
  int pos1 = cnt[tid][e1];
  int pos2 = cnt[tid][e2];
  if (pos1 < CAP) {
    size_t o = (size_t)t * EE * CAP + (size_t)e1 * CAP + pos1;
    disp[o] = 1.0f;
    comb[o] = p1[t];
  }
  if (pos2 < CAP) {
    size_t o = (size_t)t * EE * CAP + (size_t)e2 * CAP + pos2;
    disp[o] = 1.0f;
    comb[o] = p2[t];
  }
  if (c == 0 && tid == 0) {
    float aux = 0.f;
    for (int e = 0; e < EE; ++e) {
      int tot = 0;
      for (int cc = 0; cc < 16; ++cc) tot += hist[cc * EE + e];
      aux += (psum[e] / (float)NTOK) * ((float)tot / (float)NASSIGN);
    }
    aux_out[0] = aux * (float)EE;
  }
}

// ---------------- fp32 fallback GEMM (+ old softmax path) ----------------
__global__ __launch_bounds__(256) void k_gemm_f32(
    const float* __restrict__ X, const float* __restrict__ w1,
    const float* __restrict__ b1, const float* __restrict__ w2,
    float* __restrict__ logits) {
  __shared__ float Asf[16][65];
  __shared__ float Bsf[16][64];
  __shared__ float w2sf[64][EE];
  int tid = threadIdx.x;
  int m0 = blockIdx.x * 64, n0 = blockIdx.y * 64;
  for (int i = tid; i < 64 * EE; i += 256)
    w2sf[i / EE][i % EE] = w2[(size_t)(n0 + i / EE) * EE + (i % EE)];
  float acc[4][4] = {};
  int tx = tid & 15, ty = tid >> 4;
  for (int k0 = 0; k0 < HH; k0 += 16) {
    for (int idx = tid; idx < 64 * 16; idx += 256) {
      int m = idx >> 4, kk = idx & 15;
      Asf[kk][m] = X[(size_t)(m0 + m) * HH + k0 + kk];
    }
    for (int idx = tid; idx < 16 * 64; idx += 256) {
      int kk = idx >> 6, n = idx & 63;
      Bsf[kk][n] = w1[(size_t)(k0 + kk) * HH + n0 + n];
    }
    __syncthreads();
    for (int kk = 0; kk < 16; ++kk) {
      float a[4], bb[4];
      for (int i = 0; i < 4; ++i) a[i] = Asf[kk][ty * 4 + i];
      for (int j = 0; j < 4; ++j) bb[j] = Bsf[kk][tx * 4 + j];
      for (int i = 0; i < 4; ++i)
        for (int j = 0; j < 4; ++j) acc[i][j] += a[i] * bb[j];
    }
    __syncthreads();
  }
  float p[4][EE] = {};
  for (int i = 0; i < 4; ++i)
    for (int j = 0; j < 4; ++j) {
      int c = tx * 4 + j;
      float v = fmaxf(acc[i][j] + b1[n0 + c], 0.f);
      for (int e = 0; e < EE; ++e) p[i][e] += v * w2sf[c][e];
    }
  for (int m = 1; m < 16; m <<= 1)
    for (int i = 0; i < 4; ++i)
      for (int e = 0; e < EE; ++e) p[i][e] += __shfl_xor(p[i][e], m);
  if (tx == 0)
    for (int i = 0; i < 4; ++i)
      for (int e = 0; e < EE; ++e)
        atomicAdd(&logits[(size_t)(m0 + ty * 4 + i) * EE + e], p[i][e]);
}

__global__ void k_init_logits(const float* __restrict__ adj, const float* __restrict__ b2,
                              float* __restrict__ logits) {
  int i = blockIdx.x * 256 + threadIdx.x;
  int e = i & 7;
  int t = i >> 3;
  int b = t >> 11;
  logits[i] = b2[e] + adj[b * EE + e];
}

__global__ void k_softmax(const float* __restrict__ logits, float* __restrict__ probs_out,
                          int* __restrict__ idx_pack, float* __restrict__ p1o,
                          float* __restrict__ p2o, float* __restrict__ psum) {
  int t = blockIdx.x * 256 + threadIdx.x;
  float l[EE];
  float mx = -1e30f;
  for (int e = 0; e < EE; ++e) { l[e] = logits[t * EE + e]; mx = fmaxf(mx, l[e]); }
  float s = 0.f;
  for (int e = 0; e < EE; ++e) { l[e] = expf(l[e] - mx); s += l[e]; }
  float inv = 1.f / s;
  for (int e = 0; e < EE; ++e) { l[e] *= inv; probs_out[t * EE + e] = l[e]; }
  int e1 = 0; float p1 = l[0];
  for (int e = 1; e < EE; ++e) if (l[e] > p1) { p1 = l[e]; e1 = e; }
  int e2 = -1; float p2 = -1.f;
  for (int e = 0; e < EE; ++e) if (e != e1 && l[e] > p2) { p2 = l[e]; e2 = e; }
  float norm = 1.f / (p1 + p2 + 1e-8f);
  idx_pack[t] = e1 | (e2 << 8);
  p1o[t] = p1 * norm;
  p2o[t] = p2 * norm;
  for (int m = 1; m < 64; m <<= 1)
    for (int e = 0; e < EE; ++e) l[e] += __shfl_xor(l[e], m);
  if ((threadIdx.x & 63) == 0)
    for (int e = 0; e < EE; ++e) atomicAdd(&psum[e], l[e]);
}

__global__ __launch_bounds__(256) void k_route(
    const int* __restrict__ idx_pack, const float* __restrict__ p1,
    const float* __restrict__ p2, const float* __restrict__ psum,
    float* __restrict__ disp, float* __restrict__ comb, float* __restrict__ aux_out) {
  __shared__ int cnt[256][EE];
  __shared__ int tot[EE];
  int tid = threadIdx.x;
  const int CH = NASSIGN / 256;
  int n0 = tid * CH;
  int local[EE] = {};
  for (int n = n0; n < n0 + CH; ++n) {
    int t = n >> 1;
    int pk = idx_pack[t];
    int e = (n & 1) ? (pk >> 8) : (pk & 0xff);
    local[e]++;
  }
  for (int e = 0; e < EE; ++e) cnt[tid][e] = local[e];
  __syncthreads();
  if (tid < EE) {
    int run = 0;
    for (int t = 0; t < 256; ++t) { int v = cnt[t][tid]; cnt[t][tid] = run; run += v; }
    tot[tid] = run;
  }
  __syncthreads();
  int off[EE];
  for (int e = 0; e < EE; ++e) off[e] = cnt[tid][e];
  for (int n = n0; n < n0 + CH; ++n) {
    int t = n >> 1;
    int pk = idx_pack[t];
    int e; float p;
    if (n & 1) { e = pk >> 8; p = p2[t]; } else { e = pk & 0xff; p = p1[t]; }
    int pos = off[e]++;
    if (pos < CAP) {
      size_t o = (size_t)t * EE * CAP + (size_t)e * CAP + pos;
      disp[o] = 1.0f;
      comb[o] = p;
    }
  }
  if (tid == 0) {
    float aux = 0.f;
    for (int e = 0; e < EE; ++e)
      aux += (psum[e] / (float)NTOK) * ((float)tot[e] / (float)NASSIGN);
    aux_out[0] = aux * (float)EE;
  }
}

extern "C" void kernel_launch(void* const* d_in, const int* in_sizes, int n_in,
                              void* d_out, int out_size, void* d_ws, size_t ws_size,
                              hipStream_t stream) {
  const float* x   = (const float*)d_in[0];
  const float* w1  = (const float*)d_in[1];
  const float* b1  = (const float*)d_in[2];
  const float* w2  = (const float*)d_in[3];
  const float* b2  = (const float*)d_in[4];
  const float* wc1 = (const float*)d_in[5];
  const float* bc1 = (const float*)d_in[6];
  const float* wc2 = (const float*)d_in[7];
  const float* bc2 = (const float*)d_in[8];
  const float* chr = (const float*)d_in[9];

  float* out = (float*)d_out;
  float* disp  = out;
  float* comb  = disp + (size_t)NTOK * EE * CAP;
  float* probs = comb + (size_t)NTOK * EE * CAP;
  float* aux   = probs + (size_t)NTOK * EE;

  float* ws = (float*)d_ws;
  float* psum   = ws + WS_PSUM;
  float* hcr    = ws + WS_HC;
  float* adj    = ws + WS_ADJ;
  float* p1     = ws + WS_P1;
  float* p2     = ws + WS_P2;
  int*   idxp   = (int*)(ws + WS_IDX);
  float* logits = ws + WS_LOGITS;           // fallback only
  float* avgp   = ws + WS_LOGITS;           // avg partials (mfma + fallback pre-gemm)

  char* wsb = (char*)d_ws;
  unsigned short* Xh = (unsigned short*)(wsb + WS_BF16_BYTE);
  unsigned short* Xm = Xh + (size_t)NTOK * HH;
  unsigned short* Wh = Xm + (size_t)NTOK * HH;
  unsigned short* Wm = Wh + (size_t)HH * HH;
  float* plg  = (float*)(wsb + WS_H_BYTE);             // [32][4096][8] = 4MB
  int*   hist = (int*)(wsb + WS_H_BYTE + 4194304);     // [16][8]

  bool use_mfma = ws_size >= WS_NEED;

  if (use_mfma) {
    // D1: prep_x + prep_w (2-plane split) + avg partials + ws-head zero
    k_prep<<<PREPX_BLKS + PREPW_BLKS + AVG_BLKS, 256, 0, stream>>>(
        x, w1, Xh, Xm, Wh, Wm, ws, avgp);
    // D2: hc (atomics into hc_raw zeroed in D1)
    k_hc<<<dim3(HH / 256, 8, BB), 256, 0, stream>>>(avgp, chr, wc1, hcr);
    // D3: 512 GEMM blocks (4-term, BK=64, in-loop NT zeroing; plg epilogue)
    //     + 2 adj blocks
    k_gemm_mfma<<<dim3(NTOK / BM, HH / BN + 1), 256, 0, stream>>>(
        Xh, Xm, Wh, Wm, b1, w2, plg, (f32x4*)d_out,
        hcr, bc1, wc2, bc2, adj);
    // D4: slice-sum + softmax + top2 + psum + chunk histograms (16 blocks)
    k_logits2<<<NTOK / 256, 256, 0, stream>>>(plg, b2, adj, probs, idxp, p1, p2,
                                              psum, hist);
    // D5: parallel serial-order capacity + scatter + aux (16 blocks)
    k_route3<<<16, 256, 0, stream>>>(idxp, p1, p2, hist, psum, disp, comb, aux);
  } else {
    hipMemsetAsync(d_ws, 0, WS_ZERO_BYTES, stream);
    hipMemsetAsync(d_out, 0, (size_t)out_size * sizeof(float), stream);
    k_avgp<<<dim3(HH / 256, 16, BB), 256, 0, stream>>>(x, avgp);
    k_hc<<<dim3(HH / 256, 8, BB), 256, 0, stream>>>(avgp, chr, wc1, hcr);
    k_adj<<<BB, 256, 0, stream>>>(hcr, bc1, wc2, bc2, adj);
    k_init_logits<<<(NTOK * EE) / 256, 256, 0, stream>>>(adj, b2, logits);
    k_gemm_f32<<<dim3(NTOK / 64, HH / 64), 256, 0, stream>>>(x, w1, b1, w2, logits);
    k_softmax<<<NTOK / 256, 256, 0, stream>>>(logits, probs, idxp, p1, p2, psum);
    k_route<<<1, 256, 0, stream>>>(idxp, p1, p2, psum, disp, comb, aux);
  }
}